// Round 1
// baseline (776.202 us; speedup 1.0000x reference)
//
#include <hip/hip_runtime.h>
#include <stdint.h>

#define ROWLEN 4096
#define KSEL   1024
#define NTHREADS 256

// Monotonic float->uint map: order(f) preserved as unsigned compare.
__device__ __forceinline__ uint32_t f2u_sortable(float f) {
    uint32_t u = __float_as_uint(f);
    return u ^ ((int32_t)u < 0 ? 0xFFFFFFFFu : 0x80000000u);
}

__global__ __launch_bounds__(NTHREADS) void adaptive_topk_kernel(
    const float* __restrict__ in, int* __restrict__ out_idx, int* __restrict__ out_k)
{
    __shared__ uint32_t sv[ROWLEN];                 // 16 KB staged sortable values
    __shared__ unsigned long long keys[KSEL];       // 8 KB selected 44-bit keys
    __shared__ uint32_t hist[NTHREADS];             // 256 bins
    __shared__ double wsum[4], wsum2[4];
    __shared__ int sh_digit, sh_rem, cnt;

    const int row = blockIdx.x;
    const int tid = threadIdx.x;
    const float* __restrict__ rowp = in + (size_t)row * ROWLEN;

    // ---- load row (float4), convert to sortable u32 into LDS, accumulate moments ----
    double s = 0.0, s2 = 0.0;
    const float4* r4 = (const float4*)rowp;
    for (int i = tid; i < ROWLEN / 4; i += NTHREADS) {
        float4 v = r4[i];
        s  += (double)v.x + (double)v.y + (double)v.z + (double)v.w;
        s2 += (double)v.x * v.x + (double)v.y * v.y + (double)v.z * v.z + (double)v.w * v.w;
        uint4 w;
        w.x = f2u_sortable(v.x);
        w.y = f2u_sortable(v.y);
        w.z = f2u_sortable(v.z);
        w.w = f2u_sortable(v.w);
        ((uint4*)sv)[i] = w;
    }

    // ---- block reduction for variance -> k_values ----
    for (int off = 32; off > 0; off >>= 1) {
        s  += __shfl_down(s, off);
        s2 += __shfl_down(s2, off);
    }
    if ((tid & 63) == 0) { wsum[tid >> 6] = s; wsum2[tid >> 6] = s2; }
    __syncthreads();
    if (tid == 0) {
        double S  = wsum[0] + wsum[1] + wsum[2] + wsum[3];
        double S2 = wsum2[0] + wsum2[1] + wsum2[2] + wsum2[3];
        double var = (S2 - S * S / (double)ROWLEN) / (double)(ROWLEN - 1);
        float sp = log1pf(expf((float)var));          // softplus
        float ka = 512.0f * (1.0f + 0.1f * sp);
        ka = fminf(fmaxf(ka, 128.0f), 1024.0f);
        out_k[row] = (int)ka;                          // truncation, like .astype(int32)
    }

    // ---- radix-select the 1024th-largest 44-bit key ----
    // key = (sortable_value << 12) | (4095 - idx)  -> all keys distinct;
    // descending key order == value desc, idx asc (lax.top_k tie-break).
    unsigned long long prefix = 0;
    int remaining = KSEL;
    for (int pass = 0; pass < 6; ++pass) {
        const int shift = (pass < 5) ? (36 - 8 * pass) : 0;
        const int prevShift = 44 - 8 * pass;   // bits already fixed start here (pass>=1)
        hist[tid] = 0;
        __syncthreads();
        for (int i = tid; i < ROWLEN; i += NTHREADS) {
            unsigned long long K = ((unsigned long long)sv[i] << 12) | (unsigned)(ROWLEN - 1 - i);
            bool ok = (pass == 0) || ((K >> prevShift) == prefix);
            if (ok) {
                unsigned d = (pass < 5) ? (unsigned)((K >> shift) & 0xFF) : (unsigned)(K & 0xF);
                atomicAdd(&hist[d], 1u);
            }
        }
        __syncthreads();
        // parallel suffix sum: hist[d] := count of digits >= d
        for (int off = 1; off < NTHREADS; off <<= 1) {
            uint32_t t = (tid + off < NTHREADS) ? hist[tid + off] : 0u;
            __syncthreads();
            hist[tid] += t;
            __syncthreads();
        }
        uint32_t ge     = hist[tid];
        uint32_t geNext = (tid + 1 < NTHREADS) ? hist[tid + 1] : 0u;
        if (ge >= (uint32_t)remaining && geNext < (uint32_t)remaining) {
            sh_digit = tid;
            sh_rem   = remaining - (int)geNext;
        }
        __syncthreads();
        const int w = (pass < 5) ? 8 : 4;
        prefix = (prefix << w) | (unsigned)sh_digit;
        remaining = sh_rem;
        __syncthreads();
    }
    // prefix == exact threshold key K*; exactly KSEL keys are >= K*.

    // ---- compact selected keys into LDS ----
    if (tid == 0) cnt = 0;
    __syncthreads();
    for (int i = tid; i < ROWLEN; i += NTHREADS) {
        unsigned long long K = ((unsigned long long)sv[i] << 12) | (unsigned)(ROWLEN - 1 - i);
        if (K >= prefix) {
            int pos = atomicAdd(&cnt, 1);
            if (pos < KSEL) keys[pos] = K;
        }
    }
    __syncthreads();

    // ---- bitonic sort KSEL keys, descending ----
    for (int k = 2; k <= KSEL; k <<= 1) {
        for (int j = k >> 1; j > 0; j >>= 1) {
            for (int i = tid; i < KSEL; i += NTHREADS) {
                int ixj = i ^ j;
                if (ixj > i) {
                    unsigned long long a = keys[i], b = keys[ixj];
                    bool up = ((i & k) == 0);
                    if (up ? (a < b) : (a > b)) { keys[i] = b; keys[ixj] = a; }
                }
            }
            __syncthreads();
        }
    }

    // ---- write indices ----
    int* orow = out_idx + (size_t)row * KSEL;
    for (int i = tid; i < KSEL; i += NTHREADS) {
        orow[i] = (ROWLEN - 1) - (int)(keys[i] & 0xFFFu);
    }
}

extern "C" void kernel_launch(void* const* d_in, const int* in_sizes, int n_in,
                              void* d_out, int out_size, void* d_ws, size_t ws_size,
                              hipStream_t stream) {
    const float* in = (const float*)d_in[0];
    const int B = in_sizes[0] / (ROWLEN * ROWLEN);   // 4
    const int nrows = B * ROWLEN;                    // 16384
    int* out = (int*)d_out;
    int* out_idx = out;                              // B*L*KSEL
    int* out_k   = out + (size_t)nrows * KSEL;       // B*L
    adaptive_topk_kernel<<<dim3(nrows), dim3(NTHREADS), 0, stream>>>(in, out_idx, out_k);
}

// Round 2
// 363.905 us; speedup vs baseline: 2.1330x; 2.1330x over previous
//
#include <hip/hip_runtime.h>
#include <stdint.h>

#define ROWLEN 4096
#define KSEL   1024
#define NTHREADS 256
typedef unsigned long long u64;

// Monotonic float->uint map: order(f) preserved as unsigned compare.
__device__ __forceinline__ uint32_t f2u_sortable(float f) {
    uint32_t u = __float_as_uint(f);
    return u ^ ((int32_t)u < 0 ? 0xFFFFFFFFu : 0x80000000u);
}

__device__ __forceinline__ void cmpex(u64 &a, u64 &b, bool maxFirst) {
    u64 mx = a > b ? a : b;
    u64 mn = a > b ? b : a;
    a = maxFirst ? mx : mn;
    b = maxFirst ? mn : mx;
}

// hist[NB] filled. Find digit d with S(d) < need <= S(d)+hist[d] where
// S(d) = #elements in bins > d. Writes sh_digit=d, sh_base=S(d).
// 2 barriers. Chunk-per-thread + wave shuffle suffix scan.
template<int NB>
__device__ void suffix_select(uint32_t* hist, int need, int tid,
                              int* sh_digit, int* sh_base, uint32_t* wavetot)
{
    constexpr int BPT = NB / NTHREADS;
    const int b0 = tid * BPT;
    uint32_t hh[BPT];
    uint32_t csum = 0;
#pragma unroll
    for (int b = 0; b < BPT; ++b) { hh[b] = hist[b0 + b]; csum += hh[b]; }
    const int lane = tid & 63;
    uint32_t incl = csum;                  // inclusive suffix over chunk sums in wave
#pragma unroll
    for (int off = 1; off < 64; off <<= 1) {
        uint32_t t = __shfl_down(incl, off);
        if (lane + off < 64) incl += t;
    }
    const int w = tid >> 6;
    if (lane == 0) wavetot[w] = incl;      // wave total
    __syncthreads();
    uint32_t later = 0;
    for (int ww = w + 1; ww < 4; ++ww) later += wavetot[ww];
    uint32_t run = (incl - csum) + later;  // elements in chunks after mine
#pragma unroll
    for (int b = BPT - 1; b >= 0; --b) {   // bins high -> low inside chunk
        uint32_t h = hh[b];
        if ((int)run < need && need <= (int)(run + h)) {
            *sh_digit = b0 + b;
            *sh_base  = (int)run;
        }
        run += h;
    }
    __syncthreads();
}

__global__ __launch_bounds__(NTHREADS) void adaptive_topk_kernel(
    const float* __restrict__ in, int* __restrict__ out_idx, int* __restrict__ out_k)
{
    __shared__ uint32_t sv[ROWLEN];        // 16 KB sortable values
    __shared__ u64 keysbuf[KSEL];          // 8 KB; aliased as hist[2048] during select
    __shared__ uint32_t eq[256];           // equal-to-threshold indices
    __shared__ uint32_t wavetot[4];
    __shared__ double wsum[4], wsum2[4];
    __shared__ int sh_digit, sh_base, sh_cnt, sh_eqn;

    uint32_t* hist = (uint32_t*)keysbuf;
    u64* keys = keysbuf;

    const int row  = blockIdx.x;
    const int tid  = threadIdx.x;
    const int lane = tid & 63;
    const float* __restrict__ rowp = in + (size_t)row * ROWLEN;

    // ---- clear hist ----
    for (int b = tid; b < 2048; b += NTHREADS) hist[b] = 0;
    __syncthreads();

    // ---- load row: moments + sv + 11-bit histogram, fused ----
    double s = 0.0, s2 = 0.0;
    const float4* r4 = (const float4*)rowp;
    for (int i = tid; i < ROWLEN / 4; i += NTHREADS) {
        float4 v = r4[i];
        s  += (double)v.x + (double)v.y + (double)v.z + (double)v.w;
        s2 += (double)v.x * v.x + (double)v.y * v.y + (double)v.z * v.z + (double)v.w * v.w;
        uint4 w;
        w.x = f2u_sortable(v.x);
        w.y = f2u_sortable(v.y);
        w.z = f2u_sortable(v.z);
        w.w = f2u_sortable(v.w);
        ((uint4*)sv)[i] = w;
        atomicAdd(&hist[w.x >> 21], 1u);
        atomicAdd(&hist[w.y >> 21], 1u);
        atomicAdd(&hist[w.z >> 21], 1u);
        atomicAdd(&hist[w.w >> 21], 1u);
    }
    // variance partial reduce (wave)
    for (int off = 32; off > 0; off >>= 1) {
        s  += __shfl_down(s, off);
        s2 += __shfl_down(s2, off);
    }
    if (lane == 0) { wsum[tid >> 6] = s; wsum2[tid >> 6] = s2; }
    __syncthreads();   // covers sv, hist, wsum
    if (tid == 0) {
        double S  = wsum[0] + wsum[1] + wsum[2] + wsum[3];
        double S2 = wsum2[0] + wsum2[1] + wsum2[2] + wsum2[3];
        double var = (S2 - S * S / (double)ROWLEN) / (double)(ROWLEN - 1);
        float sp = log1pf(expf((float)var));
        float ka = 512.0f * (1.0f + 0.1f * sp);
        ka = fminf(fmaxf(ka, 128.0f), 1024.0f);
        out_k[row] = (int)ka;
    }

    // ---- pass 1: top 11 bits ----
    suffix_select<2048>(hist, KSEL, tid, &sh_digit, &sh_base, wavetot);
    const int d1 = sh_digit;
    const int G1 = sh_base;
    const int rem1 = KSEL - G1;

    // ---- pass 2: next 11 bits among digit1==d1 ----
    for (int b = tid; b < 2048; b += NTHREADS) hist[b] = 0;
    __syncthreads();
    for (int i = tid; i < ROWLEN; i += NTHREADS) {
        uint32_t v = sv[i];
        if ((int)(v >> 21) == d1) atomicAdd(&hist[(v >> 10) & 0x7FF], 1u);
    }
    __syncthreads();
    suffix_select<2048>(hist, rem1, tid, &sh_digit, &sh_base, wavetot);
    const int d2 = sh_digit;
    const int G2 = sh_base;
    const int rem2 = rem1 - G2;
    const uint32_t pfx21 = (((uint32_t)d1) << 11) | (uint32_t)d2;

    // ---- pass 3: last 10 bits ----
    for (int b = tid; b < 2048; b += NTHREADS) hist[b] = 0;
    __syncthreads();
    for (int i = tid; i < ROWLEN; i += NTHREADS) {
        uint32_t v = sv[i];
        if ((v >> 10) == pfx21) atomicAdd(&hist[v & 0x3FF], 1u);
    }
    __syncthreads();
    suffix_select<1024>(hist, rem2, tid, &sh_digit, &sh_base, wavetot);
    const int d3 = sh_digit;
    const int G3 = sh_base;
    const int NG = G1 + G2 + G3;          // #elements with value > v*
    const int T  = rem2 - G3;             // #equal-to-v* to take (smallest indices)
    const int E  = (int)hist[d3];         // #elements equal to v*
    const uint32_t vstar = (((uint32_t)d1) << 21) | (((uint32_t)d2) << 10) | (uint32_t)d3;
    if (tid == 0) { sh_cnt = 0; sh_eqn = 0; }
    __syncthreads();   // everyone has read hist (aliased by keys below)

    // ---- compact: v > v* via ballot-aggregated append; v == v* to eq list ----
    for (int i = tid; i < ROWLEN; i += NTHREADS) {
        uint32_t v = sv[i];
        bool gt = v > vstar;
        u64 m = __ballot(gt);
        int wbase = 0;
        if (lane == 0 && m) wbase = atomicAdd(&sh_cnt, __popcll(m));
        wbase = __shfl(wbase, 0);
        if (gt) {
            int pos = wbase + __popcll(m & ((1ull << lane) - 1ull));
            keys[pos] = ((u64)v << 12) | (u64)(ROWLEN - 1 - i);
        }
        if (v == vstar) {
            int e = atomicAdd(&sh_eqn, 1);
            if (e < 256) eq[e] = (uint32_t)i;
        }
    }
    __syncthreads();

    // ---- equals: take T smallest indices among E equal elements ----
    if (E <= 256) {
        for (int e = tid; e < E; e += NTHREADS) {
            uint32_t idx = eq[e];
            int r = 0;
            for (int j = 0; j < E; ++j) r += (eq[j] < idx);
            if (r < T) keys[NG + r] = ((u64)vstar << 12) | (u64)(ROWLEN - 1 - idx);
        }
    } else if (tid == 0) {   // degenerate fallback (massive duplication)
        int taken = 0;
        for (int i = 0; i < ROWLEN && taken < T; ++i)
            if (sv[i] == vstar) { keys[NG + taken] = ((u64)vstar << 12) | (u64)(ROWLEN - 1 - i); ++taken; }
    }
    __syncthreads();

    // ---- bitonic sort 1024 keys descending: 4 keys/thread in registers,
    //      j=1,2 in-reg, j=4..128 shfl_xor, j=256,512 via LDS (6 barriers) ----
    u64 r[4];
#pragma unroll
    for (int e = 0; e < 4; ++e) r[e] = keys[(tid << 2) | e];

#pragma unroll
    for (int k = 2; k <= KSEL; k <<= 1) {
#pragma unroll
        for (int j = k >> 1; j > 0; j >>= 1) {
            if (j >= 256) {
#pragma unroll
                for (int e = 0; e < 4; ++e) keys[(tid << 2) | e] = r[e];
                __syncthreads();
                u64 o[4];
#pragma unroll
                for (int e = 0; e < 4; ++e) o[e] = keys[((tid << 2) | e) ^ j];
                __syncthreads();
#pragma unroll
                for (int e = 0; e < 4; ++e) {
                    int i = (tid << 2) | e;
                    bool takeMax = (((i & j) == 0) == ((i & k) == 0));
                    u64 a = r[e], b = o[e];
                    u64 mx = a > b ? a : b, mn = a > b ? b : a;
                    r[e] = takeMax ? mx : mn;
                }
            } else if (j >= 4) {
                int msk = j >> 2;
#pragma unroll
                for (int e = 0; e < 4; ++e) {
                    u64 o = __shfl_xor(r[e], msk);
                    int i = (tid << 2) | e;
                    bool takeMax = (((i & j) == 0) == ((i & k) == 0));
                    u64 a = r[e];
                    u64 mx = a > o ? a : o, mn = a > o ? o : a;
                    r[e] = takeMax ? mx : mn;
                }
            } else if (j == 2) {
                int base = tid << 2;
                cmpex(r[0], r[2], ((base | 0) & k) == 0);
                cmpex(r[1], r[3], ((base | 1) & k) == 0);
            } else {
                int base = tid << 2;
                cmpex(r[0], r[1], ((base | 0) & k) == 0);
                cmpex(r[2], r[3], ((base | 2) & k) == 0);
            }
        }
    }

    // ---- write indices (coalesced int4 straight from registers) ----
    int4 ov;
    ov.x = (ROWLEN - 1) - (int)(r[0] & 0xFFFu);
    ov.y = (ROWLEN - 1) - (int)(r[1] & 0xFFFu);
    ov.z = (ROWLEN - 1) - (int)(r[2] & 0xFFFu);
    ov.w = (ROWLEN - 1) - (int)(r[3] & 0xFFFu);
    ((int4*)(out_idx + (size_t)row * KSEL))[tid] = ov;
}

extern "C" void kernel_launch(void* const* d_in, const int* in_sizes, int n_in,
                              void* d_out, int out_size, void* d_ws, size_t ws_size,
                              hipStream_t stream) {
    const float* in = (const float*)d_in[0];
    const int B = in_sizes[0] / (ROWLEN * ROWLEN);   // 4
    const int nrows = B * ROWLEN;                    // 16384
    int* out = (int*)d_out;
    int* out_idx = out;                              // B*L*KSEL
    int* out_k   = out + (size_t)nrows * KSEL;       // B*L
    adaptive_topk_kernel<<<dim3(nrows), dim3(NTHREADS), 0, stream>>>(in, out_idx, out_k);
}